// Round 1
// baseline (172.365 us; speedup 1.0000x reference)
//
#include <hip/hip_runtime.h>
#include <math.h>

// Problem constants
#define NB 4      // batch
#define TD 128    // T_DEC
#define SE 1024   // S_ENC
#define DD 512    // D
#define UN 128    // UNITS

// tanh(x) = 1 - 2/(exp(2x)+1); rcp approx error ~1e-5, fine vs 3e-3 tolerance.
// exp(2x)->inf => rcp->0 => +1;  exp(2x)->0 => 1-2 = -1. Stable at both ends.
__device__ __forceinline__ float fast_tanh(float x) {
  float e = __expf(2.0f * x);
  return 1.0f - 2.0f * __builtin_amdgcn_rcpf(e + 1.0f);
}

// K1: w_enc[row, u] = enc[row,:] . W1[:,u] + b1[u]   (rows = B*S = 4096)
// 4 waves/WG, 4 rows/wave, 2 u-cols/lane. grid = 4096/16 = 256 WGs.
// W1 float2 loads are lane-contiguous (512B/wave); enc float4 loads are
// wave-uniform (single 16B line).
__global__ __launch_bounds__(256) void k_wenc(const float* __restrict__ enc,
                                              const float* __restrict__ W1,
                                              const float* __restrict__ b1,
                                              float* __restrict__ wenc) {
  const int wave = threadIdx.x >> 6;
  const int lane = threadIdx.x & 63;
  const int row0 = (blockIdx.x * 4 + wave) * 4;   // 4 rows per wave
  const int u0 = lane * 2;
  const float* erow = enc + (size_t)row0 * DD;
  float acc[4][2] = {};
  for (int k0 = 0; k0 < DD; k0 += 4) {
    float4 e[4];
#pragma unroll
    for (int r = 0; r < 4; ++r)
      e[r] = *(const float4*)(erow + (size_t)r * DD + k0);
#pragma unroll
    for (int kk = 0; kk < 4; ++kk) {
      float2 w = *(const float2*)(W1 + (size_t)(k0 + kk) * UN + u0);
#pragma unroll
      for (int r = 0; r < 4; ++r) {
        const float* ep = (const float*)&e[r];
        float ev = ep[kk];
        acc[r][0] = fmaf(ev, w.x, acc[r][0]);
        acc[r][1] = fmaf(ev, w.y, acc[r][1]);
      }
    }
  }
  float2 bb = *(const float2*)(b1 + u0);
#pragma unroll
  for (int r = 0; r < 4; ++r) {
    float2 o;
    o.x = acc[r][0] + bb.x;
    o.y = acc[r][1] + bb.y;
    *(float2*)(wenc + (size_t)(row0 + r) * UN + u0) = o;
  }
}

// K2: one WG per (b,t).  Phase A: w_dec row (+b2) into LDS (2 threads per u,
// each half of K).  Phase B: each thread scores 4 s-values (s = tx + i*256):
// score = v . tanh(w_enc[b,s,:] + wd[:]) + v_b.  Phase C: block softmax via
// wave shuffles + tiny LDS cross-wave reduce; write attn row (coalesced).
__global__ __launch_bounds__(256) void k_attn(const float* __restrict__ dec,
                                              const float* __restrict__ W2,
                                              const float* __restrict__ b2,
                                              const float* __restrict__ v,
                                              const float* __restrict__ vb,
                                              const float* __restrict__ wenc,
                                              float* __restrict__ attn) {
  __shared__ __align__(16) float wd[UN];
  __shared__ __align__(16) float vsh[UN];
  __shared__ float redA[4];
  __shared__ float redB[4];
  const int bt = blockIdx.x;       // 0..511
  const int b = bt >> 7;
  const int tx = threadIdx.x;

  // Phase A: w_dec row
  {
    const float* drow = dec + (size_t)bt * DD;
    const int u = tx & 127;
    const int half = tx >> 7;      // 0 or 1
    float s = 0.f;
    const int kbeg = half * 256;
    for (int k = kbeg; k < kbeg + 256; k += 4) {
      float4 dv = *(const float4*)(drow + k);
      s = fmaf(dv.x, W2[(size_t)(k + 0) * UN + u], s);
      s = fmaf(dv.y, W2[(size_t)(k + 1) * UN + u], s);
      s = fmaf(dv.z, W2[(size_t)(k + 2) * UN + u], s);
      s = fmaf(dv.w, W2[(size_t)(k + 3) * UN + u], s);
    }
    if (half == 0) { wd[u] = s; vsh[u] = v[u]; }
    __syncthreads();
    if (half == 1) wd[u] = wd[u] + s + b2[u];
    __syncthreads();
  }

  // Phase B: scores for 4 s-values per thread
  const float vbias = vb[0];
  float sc[4];
#pragma unroll
  for (int i = 0; i < 4; ++i) {
    const int s = tx + i * 256;
    const float* we = wenc + ((size_t)b * SE + s) * UN;
    float a0 = 0.f, a1 = 0.f, a2 = 0.f, a3 = 0.f;
    for (int u4 = 0; u4 < UN; u4 += 4) {
      float4 w = *(const float4*)(we + u4);
      float4 dd = *(const float4*)(wd + u4);
      float4 vv = *(const float4*)(vsh + u4);
      a0 = fmaf(vv.x, fast_tanh(w.x + dd.x), a0);
      a1 = fmaf(vv.y, fast_tanh(w.y + dd.y), a1);
      a2 = fmaf(vv.z, fast_tanh(w.z + dd.z), a2);
      a3 = fmaf(vv.w, fast_tanh(w.w + dd.w), a3);
    }
    sc[i] = (a0 + a1) + (a2 + a3) + vbias;
  }

  // Phase C: softmax over the 1024 scores held across the block
  float m = fmaxf(fmaxf(sc[0], sc[1]), fmaxf(sc[2], sc[3]));
#pragma unroll
  for (int off = 32; off; off >>= 1) m = fmaxf(m, __shfl_xor(m, off));
  if ((tx & 63) == 0) redA[tx >> 6] = m;
  __syncthreads();
  m = fmaxf(fmaxf(redA[0], redA[1]), fmaxf(redA[2], redA[3]));

  float p[4];
  float sum = 0.f;
#pragma unroll
  for (int i = 0; i < 4; ++i) { p[i] = __expf(sc[i] - m); sum += p[i]; }
#pragma unroll
  for (int off = 32; off; off >>= 1) sum += __shfl_xor(sum, off);
  if ((tx & 63) == 0) redB[tx >> 6] = sum;
  __syncthreads();
  sum = (redB[0] + redB[1]) + (redB[2] + redB[3]);
  const float rinv = 1.0f / sum;

  float* arow = attn + (size_t)bt * SE;
#pragma unroll
  for (int i = 0; i < 4; ++i) arow[tx + i * 256] = p[i] * rinv;
}

// K3: context[b,t,d] = sum_s attn[b,t,s] * enc[b,s,d]
// WG computes a 16t x 128d tile; thread computes 2t x 4d.  attn tile staged
// in LDS per 64-s chunk; enc read as float4 (coalesced 512B per tgroup,
// L1-shared across tgroups).  grid = 4*8*4 = 128 WGs.
__global__ __launch_bounds__(256) void k_ctx(const float* __restrict__ attn,
                                             const float* __restrict__ enc,
                                             float* __restrict__ ctx) {
  const int wg = blockIdx.x;
  const int dtile = wg & 3;            // 4 d-tiles of 128
  const int ttile = (wg >> 2) & 7;     // 8 t-tiles of 16
  const int b = wg >> 5;
  const int tx = threadIdx.x;
  const int d0 = dtile * 128 + (tx & 31) * 4;
  const int tg = tx >> 5;              // 0..7 -> t pair within tile
  __shared__ __align__(16) float atile[16][64];
  float acc[2][4] = {};
  for (int s0 = 0; s0 < SE; s0 += 64) {
    __syncthreads();
    {
      const int r = tx >> 4;           // 0..15
      const int c = (tx & 15) * 4;     // 0..60
      *(float4*)&atile[r][c] =
          *(const float4*)(attn + (size_t)(b * TD + ttile * 16 + r) * SE + s0 + c);
    }
    __syncthreads();
    const float* ebase = enc + ((size_t)b * SE + s0) * DD + d0;
    for (int ss = 0; ss < 64; ++ss) {
      float4 ev = *(const float4*)(ebase + (size_t)ss * DD);
      float a0 = atile[tg * 2 + 0][ss];
      float a1 = atile[tg * 2 + 1][ss];
      acc[0][0] = fmaf(a0, ev.x, acc[0][0]);
      acc[0][1] = fmaf(a0, ev.y, acc[0][1]);
      acc[0][2] = fmaf(a0, ev.z, acc[0][2]);
      acc[0][3] = fmaf(a0, ev.w, acc[0][3]);
      acc[1][0] = fmaf(a1, ev.x, acc[1][0]);
      acc[1][1] = fmaf(a1, ev.y, acc[1][1]);
      acc[1][2] = fmaf(a1, ev.z, acc[1][2]);
      acc[1][3] = fmaf(a1, ev.w, acc[1][3]);
    }
  }
  const int t0 = ttile * 16 + tg * 2;
#pragma unroll
  for (int tt = 0; tt < 2; ++tt) {
    float4 o = make_float4(acc[tt][0], acc[tt][1], acc[tt][2], acc[tt][3]);
    *(float4*)(ctx + (size_t)(b * TD + t0 + tt) * DD + d0) = o;
  }
}

extern "C" void kernel_launch(void* const* d_in, const int* in_sizes, int n_in,
                              void* d_out, int out_size, void* d_ws, size_t ws_size,
                              hipStream_t stream) {
  const float* dec = (const float*)d_in[0];   // [4,128,512]
  const float* enc = (const float*)d_in[1];   // [4,1024,512]
  const float* W1  = (const float*)d_in[2];   // [512,128]
  const float* b1  = (const float*)d_in[3];   // [128]
  const float* W2  = (const float*)d_in[4];   // [512,128]
  const float* b2  = (const float*)d_in[5];   // [128]
  const float* v   = (const float*)d_in[6];   // [128]
  const float* vb  = (const float*)d_in[7];   // [1]

  float* ctx  = (float*)d_out;                       // [4,128,512]
  float* attn = (float*)d_out + (size_t)NB * TD * DD; // [4,128,1024]
  float* wenc = (float*)d_ws;                        // [4,1024,128] = 2 MB scratch

  hipLaunchKernelGGL(k_wenc, dim3(256), dim3(256), 0, stream, enc, W1, b1, wenc);
  hipLaunchKernelGGL(k_attn, dim3(NB * TD), dim3(256), 0, stream,
                     dec, W2, b2, v, vb, wenc, attn);
  hipLaunchKernelGGL(k_ctx, dim3(128), dim3(256), 0, stream, attn, enc, ctx);
}

// Round 2
// 149.423 us; speedup vs baseline: 1.1535x; 1.1535x over previous
//
#include <hip/hip_runtime.h>
#include <math.h>

#define NB 4      // batch
#define TD 128    // T_DEC
#define SE 1024   // S_ENC
#define DD 512    // D
#define UN 128    // UNITS

// tanh(x) = 1 - 2/(exp(2x)+1); rcp rel-err ~1e-5 vs 3e-3 tolerance. Stable at +-inf.
__device__ __forceinline__ float fast_tanh(float x) {
  float e = __expf(2.0f * x);
  return 1.0f - 2.0f * __builtin_amdgcn_rcpf(e + 1.0f);
}

// K1: projections. rows 0..4095 -> wenc = enc@W1+b1 ; rows 4096..4607 -> wdec = dec@W2+b2.
// 4 waves/WG, 4 rows/wave, 2 u-cols/lane. grid = 4608/16 = 288 WGs.
__global__ __launch_bounds__(256) void k_proj(const float* __restrict__ enc,
                                              const float* __restrict__ dec,
                                              const float* __restrict__ W1,
                                              const float* __restrict__ b1,
                                              const float* __restrict__ W2,
                                              const float* __restrict__ b2,
                                              float* __restrict__ wenc,
                                              float* __restrict__ wdec) {
  const int wave = threadIdx.x >> 6;
  const int lane = threadIdx.x & 63;
  const int row0 = (blockIdx.x * 4 + wave) * 4;   // 4 rows per wave; boundary 4096 is 4-aligned
  const int u0 = lane * 2;
  const bool is_enc = row0 < (NB * SE);
  const float* src = is_enc ? (enc + (size_t)row0 * DD)
                            : (dec + (size_t)(row0 - NB * SE) * DD);
  const float* W = is_enc ? W1 : W2;
  const float* bias = is_enc ? b1 : b2;
  float* dst = is_enc ? (wenc + (size_t)row0 * UN)
                      : (wdec + (size_t)(row0 - NB * SE) * UN);
  float acc[4][2] = {};
  for (int k0 = 0; k0 < DD; k0 += 4) {
    float4 e[4];
#pragma unroll
    for (int r = 0; r < 4; ++r)
      e[r] = *(const float4*)(src + (size_t)r * DD + k0);
#pragma unroll
    for (int kk = 0; kk < 4; ++kk) {
      float2 w = *(const float2*)(W + (size_t)(k0 + kk) * UN + u0);
#pragma unroll
      for (int r = 0; r < 4; ++r) {
        const float* ep = (const float*)&e[r];
        float ev = ep[kk];
        acc[r][0] = fmaf(ev, w.x, acc[r][0]);
        acc[r][1] = fmaf(ev, w.y, acc[r][1]);
      }
    }
  }
  float2 bb = *(const float2*)(bias + u0);
#pragma unroll
  for (int r = 0; r < 4; ++r) {
    float2 o;
    o.x = acc[r][0] + bb.x;
    o.y = acc[r][1] + bb.y;
    *(float2*)(dst + (size_t)r * UN + u0) = o;
  }
}

// K2: one WG (512 threads, 8 waves) per (b,t). Each thread scores 2 s-values
// (s = tx, tx+512): score = v . tanh(wenc[b,s,:] + wd[:]) + v_b, then block
// softmax (wave shuffle + 8-slot LDS reduce), write attn row coalesced.
__global__ __launch_bounds__(512) void k_score(const float* __restrict__ wdec,
                                               const float* __restrict__ v,
                                               const float* __restrict__ vb,
                                               const float* __restrict__ wenc,
                                               float* __restrict__ attn) {
  __shared__ __align__(16) float wd[UN];
  __shared__ __align__(16) float vsh[UN];
  __shared__ float redA[8];
  __shared__ float redB[8];
  const int bt = blockIdx.x;       // 0..511
  const int b = bt >> 7;
  const int tx = threadIdx.x;      // 0..511

  if (tx < UN) wd[tx] = wdec[(size_t)bt * UN + tx];
  else if (tx < 2 * UN) vsh[tx - UN] = v[tx - UN];
  __syncthreads();

  const float vbias = vb[0];
  const float* we0 = wenc + ((size_t)b * SE + tx) * UN;
  const float* we1 = we0 + (size_t)512 * UN;
  float a[8] = {};   // 4 chains per score, 2 scores -> load/FMA ILP
  for (int u4 = 0; u4 < UN; u4 += 4) {
    float4 w0 = *(const float4*)(we0 + u4);
    float4 w1 = *(const float4*)(we1 + u4);
    float4 dd = *(const float4*)(wd + u4);
    float4 vv = *(const float4*)(vsh + u4);
    a[0] = fmaf(vv.x, fast_tanh(w0.x + dd.x), a[0]);
    a[1] = fmaf(vv.y, fast_tanh(w0.y + dd.y), a[1]);
    a[2] = fmaf(vv.z, fast_tanh(w0.z + dd.z), a[2]);
    a[3] = fmaf(vv.w, fast_tanh(w0.w + dd.w), a[3]);
    a[4] = fmaf(vv.x, fast_tanh(w1.x + dd.x), a[4]);
    a[5] = fmaf(vv.y, fast_tanh(w1.y + dd.y), a[5]);
    a[6] = fmaf(vv.z, fast_tanh(w1.z + dd.z), a[6]);
    a[7] = fmaf(vv.w, fast_tanh(w1.w + dd.w), a[7]);
  }
  float sc0 = (a[0] + a[1]) + (a[2] + a[3]) + vbias;
  float sc1 = (a[4] + a[5]) + (a[6] + a[7]) + vbias;

  // block max
  float m = fmaxf(sc0, sc1);
#pragma unroll
  for (int off = 32; off; off >>= 1) m = fmaxf(m, __shfl_xor(m, off));
  if ((tx & 63) == 0) redA[tx >> 6] = m;
  __syncthreads();
  m = fmaxf(fmaxf(fmaxf(redA[0], redA[1]), fmaxf(redA[2], redA[3])),
            fmaxf(fmaxf(redA[4], redA[5]), fmaxf(redA[6], redA[7])));

  float p0 = __expf(sc0 - m);
  float p1 = __expf(sc1 - m);
  float sum = p0 + p1;
#pragma unroll
  for (int off = 32; off; off >>= 1) sum += __shfl_xor(sum, off);
  if ((tx & 63) == 0) redB[tx >> 6] = sum;
  __syncthreads();
  sum = ((redB[0] + redB[1]) + (redB[2] + redB[3])) +
        ((redB[4] + redB[5]) + (redB[6] + redB[7]));
  const float rinv = 1.0f / sum;

  float* arow = attn + (size_t)bt * SE;
  arow[tx] = p0 * rinv;
  arow[tx + 512] = p1 * rinv;
}

// K3: partial context over an s-chunk of 256.
// grid: sc(4) x dtile(4) x ttile(8) x b(4) = 512 WGs. WG tile: 16t x 128d.
// thread computes 2t x 4d; attn staged in LDS per 64-s subchunk.
__global__ __launch_bounds__(256) void k_ctx_part(const float* __restrict__ attn,
                                                  const float* __restrict__ enc,
                                                  float* __restrict__ part) {
  const int wg = blockIdx.x;
  const int sc = wg & 3;
  const int dtile = (wg >> 2) & 3;
  const int ttile = (wg >> 4) & 7;
  const int b = wg >> 7;
  const int tx = threadIdx.x;
  const int d0 = dtile * 128 + (tx & 31) * 4;
  const int tg = tx >> 5;              // 0..7 -> t pair within tile
  __shared__ __align__(16) float atile[16][64];
  float acc[2][4] = {};
  const int sbeg = sc * 256;
  for (int s0 = sbeg; s0 < sbeg + 256; s0 += 64) {
    __syncthreads();
    {
      const int r = tx >> 4;           // 0..15
      const int c = (tx & 15) * 4;     // 0..60
      *(float4*)&atile[r][c] =
          *(const float4*)(attn + (size_t)(b * TD + ttile * 16 + r) * SE + s0 + c);
    }
    __syncthreads();
    const float* ebase = enc + ((size_t)b * SE + s0) * DD + d0;
    for (int ss = 0; ss < 64; ++ss) {
      float4 ev = *(const float4*)(ebase + (size_t)ss * DD);
      float a0 = atile[tg * 2 + 0][ss];
      float a1 = atile[tg * 2 + 1][ss];
      acc[0][0] = fmaf(a0, ev.x, acc[0][0]);
      acc[0][1] = fmaf(a0, ev.y, acc[0][1]);
      acc[0][2] = fmaf(a0, ev.z, acc[0][2]);
      acc[0][3] = fmaf(a0, ev.w, acc[0][3]);
      acc[1][0] = fmaf(a1, ev.x, acc[1][0]);
      acc[1][1] = fmaf(a1, ev.y, acc[1][1]);
      acc[1][2] = fmaf(a1, ev.z, acc[1][2]);
      acc[1][3] = fmaf(a1, ev.w, acc[1][3]);
    }
  }
  const int t0 = ttile * 16 + tg * 2;
#pragma unroll
  for (int tt = 0; tt < 2; ++tt) {
    float4 o = make_float4(acc[tt][0], acc[tt][1], acc[tt][2], acc[tt][3]);
    *(float4*)(part + ((size_t)sc * (NB * TD) + b * TD + t0 + tt) * DD + d0) = o;
  }
}

// K4: ctx = sum of 4 partials. 262144 floats, float4/thread, grid 256x256.
__global__ __launch_bounds__(256) void k_red(const float* __restrict__ part,
                                             float* __restrict__ ctx) {
  const size_t N = (size_t)NB * TD * DD;
  const size_t i = ((size_t)blockIdx.x * 256 + threadIdx.x) * 4;
  float4 s0 = *(const float4*)(part + i);
  float4 s1 = *(const float4*)(part + N + i);
  float4 s2 = *(const float4*)(part + 2 * N + i);
  float4 s3 = *(const float4*)(part + 3 * N + i);
  float4 o;
  o.x = (s0.x + s1.x) + (s2.x + s3.x);
  o.y = (s0.y + s1.y) + (s2.y + s3.y);
  o.z = (s0.z + s1.z) + (s2.z + s3.z);
  o.w = (s0.w + s1.w) + (s2.w + s3.w);
  *(float4*)(ctx + i) = o;
}

extern "C" void kernel_launch(void* const* d_in, const int* in_sizes, int n_in,
                              void* d_out, int out_size, void* d_ws, size_t ws_size,
                              hipStream_t stream) {
  const float* dec = (const float*)d_in[0];
  const float* enc = (const float*)d_in[1];
  const float* W1  = (const float*)d_in[2];
  const float* b1  = (const float*)d_in[3];
  const float* W2  = (const float*)d_in[4];
  const float* b2  = (const float*)d_in[5];
  const float* v   = (const float*)d_in[6];
  const float* vb  = (const float*)d_in[7];

  float* ctx  = (float*)d_out;                        // [4,128,512]
  float* attn = (float*)d_out + (size_t)NB * TD * DD; // [4,128,1024]

  float* ws   = (float*)d_ws;
  float* wenc = ws;                                   // [4096,128]  2 MB
  float* wdec = wenc + (size_t)NB * SE * UN;          // [512,128]   256 KB
  float* part = wdec + (size_t)NB * TD * UN;          // [4][512,512] 4 MB

  hipLaunchKernelGGL(k_proj, dim3(288), dim3(256), 0, stream,
                     enc, dec, W1, b1, W2, b2, wenc, wdec);
  hipLaunchKernelGGL(k_score, dim3(NB * TD), dim3(512), 0, stream,
                     wdec, v, vb, wenc, attn);
  hipLaunchKernelGGL(k_ctx_part, dim3(512), dim3(256), 0, stream, attn, enc, part);
  hipLaunchKernelGGL(k_red, dim3(256), dim3(256), 0, stream, part, ctx);
}

// Round 3
// 95.544 us; speedup vs baseline: 1.8040x; 1.5639x over previous
//
#include <hip/hip_runtime.h>
#include <math.h>

#define NB 4      // batch
#define TD 128    // T_DEC
#define SE 1024   // S_ENC
#define DD 512    // D
#define UN 128    // UNITS

// tanh(x) = 1 - 2/(exp(2x)+1). exp via __expf (v_exp); rcp via v_rcp.
// Stable at +-inf; rel err ~1e-5 << 3e-3 tolerance.

// ---------------------------------------------------------------------------
// K1: projections with LDS-staged W.
//   blocks 0..255   : 16 enc rows each -> wencT[b][u][s] (transposed via LDS)
//   blocks 256..287 : 16 dec rows each -> wdec[bt][u]    (row-major)
// 256 thr = 4 waves; wave handles 4 rows, lane covers 2 u-columns.
// W staged in 4 k-chunks of 128 (64 KB LDS), shared by all 4 waves.
__global__ __launch_bounds__(256, 1) void k_proj(const float* __restrict__ enc,
                                                 const float* __restrict__ dec,
                                                 const float* __restrict__ W1,
                                                 const float* __restrict__ b1,
                                                 const float* __restrict__ W2,
                                                 const float* __restrict__ b2,
                                                 float* __restrict__ wencT,
                                                 float* __restrict__ wdec) {
  __shared__ __align__(16) float Wl[128 * UN];   // 64 KB; reused as 16x130 tile
  float* Tt = Wl;

  const int tx = threadIdx.x;
  const int wave = tx >> 6;
  const int lane = tx & 63;
  const int blk = blockIdx.x;
  const bool is_enc = blk < 256;
  const int row_base = is_enc ? blk * 16 : (blk - 256) * 16;
  const float* src = (is_enc ? enc : dec) + (size_t)row_base * DD;
  const float* W = is_enc ? W1 : W2;
  const float* bias = is_enc ? b1 : b2;

  const int u0 = lane * 2;
  const int r0 = wave * 4;
  float acc[4][2] = {};

  for (int c = 0; c < 4; ++c) {
    __syncthreads();                       // protect Wl readers of prev chunk
    const float* Wc = W + (size_t)c * 128 * UN;
#pragma unroll
    for (int i = 0; i < 16; ++i) {
      const int idx = (i * 256 + tx) * 4;
      *(float4*)&Wl[idx] = *(const float4*)(Wc + idx);
    }
    __syncthreads();
    const int kbase = c * 128;
    for (int k0 = 0; k0 < 128; k0 += 4) {
      float4 e[4];
#pragma unroll
      for (int r = 0; r < 4; ++r)
        e[r] = *(const float4*)(src + (size_t)(r0 + r) * DD + kbase + k0);
#pragma unroll
      for (int kk = 0; kk < 4; ++kk) {
        float2 w = *(const float2*)&Wl[(k0 + kk) * UN + u0];
#pragma unroll
        for (int r = 0; r < 4; ++r) {
          const float ev = ((const float*)&e[r])[kk];
          acc[r][0] = fmaf(ev, w.x, acc[r][0]);
          acc[r][1] = fmaf(ev, w.y, acc[r][1]);
        }
      }
    }
  }
  const float2 bb = *(const float2*)(bias + u0);
  if (is_enc) {
    __syncthreads();                       // done reading Wl; reuse as Tt
#pragma unroll
    for (int r = 0; r < 4; ++r) {
      float2 o = make_float2(acc[r][0] + bb.x, acc[r][1] + bb.y);
      *(float2*)&Tt[(r0 + r) * 130 + u0] = o;   // stride 130 keeps 8B align
    }
    __syncthreads();
    const int b = (blk * 16) >> 10;
    const int s0 = (blk * 16) & 1023;
    const int u = tx >> 1;
    const int sh = tx & 1;
    float o[8];
#pragma unroll
    for (int j = 0; j < 8; ++j) o[j] = Tt[(sh * 8 + j) * 130 + u];
    float* dst = wencT + (size_t)(b * UN + u) * SE + s0 + sh * 8;
    *(float4*)dst = make_float4(o[0], o[1], o[2], o[3]);
    *(float4*)(dst + 4) = make_float4(o[4], o[5], o[6], o[7]);
  } else {
#pragma unroll
    for (int r = 0; r < 4; ++r) {
      float2 o = make_float2(acc[r][0] + bb.x, acc[r][1] + bb.y);
      *(float2*)(wdec + (size_t)(row_base + r0 + r) * UN + u0) = o;
    }
  }
}

// ---------------------------------------------------------------------------
// K2: scores + softmax. One WG (512 thr) per (b, t-pair): grid 256.
// Thread: 4 consecutive s (float4 coalesced stream over u) x 2 t x 64 u
// (u-half by wave group). wencT[b][u][s] stream is fully coalesced; wd/v are
// LDS broadcasts. v_b skipped (softmax shift-invariant).
__global__ __launch_bounds__(512, 1) void k_score(const float* __restrict__ wdec,
                                                  const float* __restrict__ v,
                                                  const float* __restrict__ wencT,
                                                  float* __restrict__ attn) {
  __shared__ __align__(16) float wd2[2][UN];        // 2*wdec row
  __shared__ __align__(16) float vsh[UN];
  __shared__ __align__(16) float parts[2][2][SE];   // [uhalf][tt][s]  16 KB
  __shared__ float redM[2][4], redS[2][4];

  const int wg = blockIdx.x;          // 0..255
  const int b = wg >> 6;
  const int t0 = (wg & 63) * 2;
  const int bt0 = b * TD + t0;
  const int tx = threadIdx.x;

  if (tx < 2 * UN) {
    const int tt = tx >> 7, u = tx & 127;
    wd2[tt][u] = 2.0f * wdec[(size_t)(bt0 + tt) * UN + u];
    if (tx < UN) vsh[tx] = v[tx];
  }
  __syncthreads();

  const int sq = tx & 255;            // s-quad 0..255
  const int uh = tx >> 8;             // u half 0/1
  const float* wp = wencT + (size_t)(b * UN + uh * 64) * SE + sq * 4;

  float a0[4] = {}, a1[4] = {};
  for (int ui = 0; ui < 64; ++ui) {
    const int u = uh * 64 + ui;
    const float4 w = *(const float4*)(wp + (size_t)ui * SE);
    const float vv = vsh[u];
    const float d0 = wd2[0][u];
    const float d1 = wd2[1][u];
#pragma unroll
    for (int j = 0; j < 4; ++j) {
      const float wj = ((const float*)&w)[j];
      float e0 = __expf(fmaf(wj, 2.0f, d0));
      float t0v = fmaf(-2.0f, __builtin_amdgcn_rcpf(e0 + 1.0f), 1.0f);
      a0[j] = fmaf(vv, t0v, a0[j]);
      float e1 = __expf(fmaf(wj, 2.0f, d1));
      float t1v = fmaf(-2.0f, __builtin_amdgcn_rcpf(e1 + 1.0f), 1.0f);
      a1[j] = fmaf(vv, t1v, a1[j]);
    }
  }
  *(float4*)&parts[uh][0][sq * 4] = make_float4(a0[0], a0[1], a0[2], a0[3]);
  *(float4*)&parts[uh][1][sq * 4] = make_float4(a1[0], a1[1], a1[2], a1[3]);
  __syncthreads();

  float sc0[4], sc1[4];
  if (tx < 256) {
    const float4 p00 = *(const float4*)&parts[0][0][tx * 4];
    const float4 p10 = *(const float4*)&parts[1][0][tx * 4];
    const float4 p01 = *(const float4*)&parts[0][1][tx * 4];
    const float4 p11 = *(const float4*)&parts[1][1][tx * 4];
    sc0[0] = p00.x + p10.x; sc0[1] = p00.y + p10.y;
    sc0[2] = p00.z + p10.z; sc0[3] = p00.w + p10.w;
    sc1[0] = p01.x + p11.x; sc1[1] = p01.y + p11.y;
    sc1[2] = p01.z + p11.z; sc1[3] = p01.w + p11.w;
    float m0 = fmaxf(fmaxf(sc0[0], sc0[1]), fmaxf(sc0[2], sc0[3]));
    float m1 = fmaxf(fmaxf(sc1[0], sc1[1]), fmaxf(sc1[2], sc1[3]));
#pragma unroll
    for (int off = 32; off; off >>= 1) {
      m0 = fmaxf(m0, __shfl_xor(m0, off));
      m1 = fmaxf(m1, __shfl_xor(m1, off));
    }
    if ((tx & 63) == 0) { redM[0][tx >> 6] = m0; redM[1][tx >> 6] = m1; }
  }
  __syncthreads();
  float p0[4], p1[4];
  if (tx < 256) {
    const float m0 = fmaxf(fmaxf(redM[0][0], redM[0][1]), fmaxf(redM[0][2], redM[0][3]));
    const float m1 = fmaxf(fmaxf(redM[1][0], redM[1][1]), fmaxf(redM[1][2], redM[1][3]));
    float s0 = 0.f, s1 = 0.f;
#pragma unroll
    for (int j = 0; j < 4; ++j) {
      p0[j] = __expf(sc0[j] - m0); s0 += p0[j];
      p1[j] = __expf(sc1[j] - m1); s1 += p1[j];
    }
#pragma unroll
    for (int off = 32; off; off >>= 1) {
      s0 += __shfl_xor(s0, off);
      s1 += __shfl_xor(s1, off);
    }
    if ((tx & 63) == 0) { redS[0][tx >> 6] = s0; redS[1][tx >> 6] = s1; }
  }
  __syncthreads();
  if (tx < 256) {
    const float s0 = (redS[0][0] + redS[0][1]) + (redS[0][2] + redS[0][3]);
    const float s1 = (redS[1][0] + redS[1][1]) + (redS[1][2] + redS[1][3]);
    const float r0 = 1.0f / s0;
    const float r1 = 1.0f / s1;
    float* arow0 = attn + (size_t)bt0 * SE + tx * 4;
    float* arow1 = arow0 + SE;
    *(float4*)arow0 = make_float4(p0[0] * r0, p0[1] * r0, p0[2] * r0, p0[3] * r0);
    *(float4*)arow1 = make_float4(p1[0] * r1, p1[1] * r1, p1[2] * r1, p1[3] * r1);
  }
}

// ---------------------------------------------------------------------------
// K3: partial context over s-chunks of 256. grid = sc(4) x tg(16) x b(4) = 256.
// WG: 8 t-rows x all 512 d; thread = 8t x 2d (16 fma per enc float2 load).
// attn tile (8x256 = 8 KB) staged in LDS, read as all-lane broadcasts.
__global__ __launch_bounds__(256, 1) void k_ctx_part(const float* __restrict__ attn,
                                                     const float* __restrict__ enc,
                                                     float* __restrict__ part) {
  __shared__ __align__(16) float at[8][256];
  const int wg = blockIdx.x;
  const int sch = wg & 3;
  const int tg = (wg >> 2) & 15;
  const int b = wg >> 6;
  const int tx = threadIdx.x;
  const int sbeg = sch * 256;
  {
    const int i = tx >> 5, c = (tx & 31) * 8;
    float4 v0 = *(const float4*)(attn + (size_t)(b * TD + tg * 8 + i) * SE + sbeg + c);
    float4 v1 = *(const float4*)(attn + (size_t)(b * TD + tg * 8 + i) * SE + sbeg + c + 4);
    *(float4*)&at[i][c] = v0;
    *(float4*)&at[i][c + 4] = v1;
  }
  __syncthreads();
  const int d0 = tx * 2;
  const float* ep = enc + ((size_t)b * SE + sbeg) * DD + d0;
  float2 acc[8] = {};
  for (int s = 0; s < 256; s += 4) {
    float4 av[8];
#pragma unroll
    for (int i = 0; i < 8; ++i) av[i] = *(const float4*)&at[i][s];
#pragma unroll
    for (int j = 0; j < 4; ++j) {
      const float2 ev = *(const float2*)(ep + (size_t)(s + j) * DD);
#pragma unroll
      for (int i = 0; i < 8; ++i) {
        const float aij = ((const float*)&av[i])[j];
        acc[i].x = fmaf(aij, ev.x, acc[i].x);
        acc[i].y = fmaf(aij, ev.y, acc[i].y);
      }
    }
  }
  float* pb = part + ((size_t)sch * (NB * TD) + b * TD + tg * 8) * DD + d0;
#pragma unroll
  for (int i = 0; i < 8; ++i)
    *(float2*)(pb + (size_t)i * DD) = acc[i];
}

// ---------------------------------------------------------------------------
// K4: ctx = sum of 4 partials. grid 256 x 256 thr, float4/thread.
__global__ __launch_bounds__(256, 1) void k_red(const float* __restrict__ part,
                                                float* __restrict__ ctx) {
  const size_t N = (size_t)NB * TD * DD;
  const size_t i = ((size_t)blockIdx.x * 256 + threadIdx.x) * 4;
  const float4 s0 = *(const float4*)(part + i);
  const float4 s1 = *(const float4*)(part + N + i);
  const float4 s2 = *(const float4*)(part + 2 * N + i);
  const float4 s3 = *(const float4*)(part + 3 * N + i);
  float4 o;
  o.x = (s0.x + s1.x) + (s2.x + s3.x);
  o.y = (s0.y + s1.y) + (s2.y + s3.y);
  o.z = (s0.z + s1.z) + (s2.z + s3.z);
  o.w = (s0.w + s1.w) + (s2.w + s3.w);
  *(float4*)(ctx + i) = o;
}

extern "C" void kernel_launch(void* const* d_in, const int* in_sizes, int n_in,
                              void* d_out, int out_size, void* d_ws, size_t ws_size,
                              hipStream_t stream) {
  const float* dec = (const float*)d_in[0];
  const float* enc = (const float*)d_in[1];
  const float* W1  = (const float*)d_in[2];
  const float* b1  = (const float*)d_in[3];
  const float* W2  = (const float*)d_in[4];
  const float* b2  = (const float*)d_in[5];
  const float* v   = (const float*)d_in[6];
  // d_in[7] = v_b: skipped — softmax is invariant to a uniform score shift.

  float* ctx  = (float*)d_out;                        // [4,128,512]
  float* attn = (float*)d_out + (size_t)NB * TD * DD; // [4,128,1024]

  float* ws    = (float*)d_ws;
  float* wencT = ws;                                  // [4][128][1024] 2 MB
  float* wdec  = wencT + (size_t)NB * UN * SE;        // [512][128] 256 KB
  float* part  = wdec + (size_t)NB * TD * UN;         // [4][512][512] 4 MB

  hipLaunchKernelGGL(k_proj, dim3(288), dim3(256), 0, stream,
                     enc, dec, W1, b1, W2, b2, wencT, wdec);
  hipLaunchKernelGGL(k_score, dim3(256), dim3(512), 0, stream,
                     wdec, v, wencT, attn);
  hipLaunchKernelGGL(k_ctx_part, dim3(256), dim3(256), 0, stream, attn, enc, part);
  hipLaunchKernelGGL(k_red, dim3(256), dim3(256), 0, stream, part, ctx);
}